// Round 2
// baseline (1143.037 us; speedup 1.0000x reference)
//
#include <hip/hip_runtime.h>
#include <math.h>

#define NKPT 17
#define MM   10
#define DD   768
#define NN   131072
#define CC   (NKPT*MM)   // 170
#define CHUNKS 16
#define GCH    8

typedef __bf16 bf16_t;
typedef bf16_t bf16x8 __attribute__((ext_vector_type(8)));
typedef float  f32x16 __attribute__((ext_vector_type(16)));

#define GLOAD_LDS16(g, s) \
    __builtin_amdgcn_global_load_lds((const __attribute__((address_space(1))) void*)(g), \
                                     (__attribute__((address_space(3))) void*)(s), 16, 0, 0)

// ---------------- proto norms: pn (fp32 normalized) + pnb (bf16, 192 rows, pad=0) ---------
__global__ __launch_bounds__(256) void k_proto_norm(const float* __restrict__ protos,
                                                    float* __restrict__ pn,
                                                    bf16_t* __restrict__ pnb) {
    int c = blockIdx.x;           // 0..191
    int t = threadIdx.x;          // 256
    if (c >= CC) {                // zero padding rows for the GEMM B-tile
        pnb[(size_t)c * DD + t]       = (bf16_t)0.f;
        pnb[(size_t)c * DD + t + 256] = (bf16_t)0.f;
        pnb[(size_t)c * DD + t + 512] = (bf16_t)0.f;
        return;
    }
    const float* row = protos + (size_t)c * DD;
    float v0 = row[t], v1 = row[t + 256], v2 = row[t + 512];
    double ss = (double)v0 * v0 + (double)v1 * v1 + (double)v2 * v2;
    __shared__ double red[256];
    red[t] = ss; __syncthreads();
    for (int s = 128; s > 0; s >>= 1) { if (t < s) red[t] += red[t + s]; __syncthreads(); }
    float invf = (float)(1.0 / fmax(sqrt(red[0]), 1e-12));
    float a0 = v0 * invf, a1 = v1 * invf, a2 = v2 * invf;
    pn[(size_t)c * DD + t]        = a0;
    pn[(size_t)c * DD + t + 256]  = a1;
    pn[(size_t)c * DD + t + 512]  = a2;
    pnb[(size_t)c * DD + t]       = (bf16_t)a0;
    pnb[(size_t)c * DD + t + 256] = (bf16_t)a1;
    pnb[(size_t)c * DD + t + 512] = (bf16_t)a2;
}

// ---------------- class histogram ----------------
__global__ __launch_bounds__(256) void k_hist(const int* __restrict__ gt,
                                              int* __restrict__ counts) {
    __shared__ int c[NKPT];
    int t = threadIdx.x;
    if (t < NKPT) c[t] = 0;
    __syncthreads();
    for (int i = blockIdx.x * blockDim.x + t; i < NN; i += gridDim.x * blockDim.x)
        atomicAdd(&c[gt[i]], 1);
    __syncthreads();
    if (t < NKPT) atomicAdd(&counts[t], c[t]);
}

__global__ void k_prefix(const int* __restrict__ counts, int* __restrict__ offsets) {
    if (threadIdx.x == 0 && blockIdx.x == 0) {
        int acc = 0;
        for (int k = 0; k < NKPT; k++) { offsets[k] = acc; acc += counts[k]; }
        offsets[NKPT] = acc;
    }
}

// ---------------- class-sort: perm (pos->row), rank (row->pos) ----------------
__global__ __launch_bounds__(256) void k_rank(const int* __restrict__ gt,
                                              const int* __restrict__ offs,
                                              int* __restrict__ cursor,
                                              int* __restrict__ perm,
                                              int* __restrict__ rank) {
    __shared__ int cnt[NKPT], base[NKPT];
    int t = threadIdx.x;
    if (t < NKPT) cnt[t] = 0;
    __syncthreads();
    int n = blockIdx.x * 256 + t;
    int cls = gt[n];
    int lr = atomicAdd(&cnt[cls], 1);
    __syncthreads();
    if (t < NKPT) base[t] = atomicAdd(&cursor[t], cnt[t]);
    __syncthreads();
    int p = offs[cls] + base[cls] + lr;
    perm[p] = n;
    rank[n] = p;
}

// ---------------- fused bf16 MFMA GEMM over SORTED rows ----------------
// Produces: o0 (|sim|, scattered to natural row order), inv_f, Es (sorted order).
// block 256 thr = 4 waves; tile 128 sorted rows x 192 cols; BK = 64.
// Precise fp32 gt-class dots + fp64 norms computed from the fp32 A-tile in LDS
// on the VALU pipe (idle in this memory-bound GEMM), between the existing barriers.
__global__ __launch_bounds__(256, 2) void k_gemm(const float* __restrict__ feats,
                                                 const bf16_t* __restrict__ pnb,
                                                 const float* __restrict__ pn,
                                                 const int* __restrict__ gt,
                                                 const int* __restrict__ perm,
                                                 float* __restrict__ inv_f,
                                                 double* __restrict__ Es,
                                                 float* __restrict__ o0) {
    __shared__ float  AsF[128 * 64];     // 32 KB fp32, 16B-chunk swizzled by (row&15)
    __shared__ bf16_t Bs[192 * 64];      // 24 KB bf16, 16B-chunk swizzled by (row&7)
    __shared__ float  pnS[2 * MM * 64];  // 5 KB: gt-class fp32 proto chunks (2 classes)
    __shared__ int    sRow[128];
    __shared__ float  sNv[128];
    int tid = threadIdx.x;
    int w = tid >> 6, l = tid & 63;
    int p0 = blockIdx.x * 128;           // sorted position base
    if (tid < 128) sRow[tid] = perm[p0 + tid];
    __syncthreads();
    int c0 = gt[sRow[0]];
    int cL = gt[sRow[127]];
    bool uniB = (c0 == cL);              // block spans at most 2 classes (sorted)

    // dot-path lane mapping: rows r0=w*32+rp, r1=r0+16; m-half mh; c-half ch
    int rp = l >> 2, mh = (l >> 1) & 1, ch = l & 1;
    int r0 = w * 32 + rp, r1 = r0 + 16;
    int nr0 = sRow[r0], nr1 = sRow[r1];
    int sel0 = (gt[nr0] == c0) ? 0 : 1;
    int sel1 = (gt[nr1] == c0) ? 0 : 1;

    // A staging bases (row-scattered source, pre-swizzled; dest stays linear)
    const float* baseA[8];
    #pragma unroll
    for (int rep = 0; rep < 8; rep++) {
        int rg = w * 8 + rep;             // 0..31
        int r  = rg * 4 + (l >> 4);
        int cg = (l & 15) ^ (r & 15);
        baseA[rep] = feats + (size_t)sRow[r] * DD + cg * 4;
    }
    // pn chunk staging bases (per-lane source, wave-uniform LDS dest)
    int pidx  = w * 64 + l;               // 0..255
    int ps    = pidx >= 160;
    int prem  = pidx - ps * 160;
    int pcls  = ps ? cL : c0;
    const float* basePn = pn + (size_t)(pcls * MM + (prem >> 4)) * DD + (prem & 15) * 4;
    int pidx2 = 256 + l;                  // wave 0 second inst: 256..319 (s=1)
    int prem2 = pidx2 - 160;
    const float* basePn2 = pn + (size_t)(cL * MM + (prem2 >> 4)) * DD + (prem2 & 15) * 4;

    f32x16 acc[6];
    #pragma unroll
    for (int ct = 0; ct < 6; ct++)
        #pragma unroll
        for (int i = 0; i < 16; i++) acc[ct][i] = 0.f;
    float d0[5], d1[5];
    #pragma unroll
    for (int j = 0; j < 5; j++) { d0[j] = 0.f; d1[j] = 0.f; }
    double ss0 = 0.0, ss1 = 0.0;

    char* AsB = (char*)AsF;
    char* BsB = (char*)Bs;
    char* pnB = (char*)pnS;
    int am = l & 31, q = l >> 5;

    for (int kc = 0; kc < DD; kc += 64) {
        // A: 32 KB, 8 insts/wave
        #pragma unroll
        for (int rep = 0; rep < 8; rep++) {
            int rg = w * 8 + rep;
            GLOAD_LDS16(baseA[rep] + kc, AsB + rg * 1024);
        }
        // B: 24 KB, 6 insts/wave
        #pragma unroll
        for (int rep = 0; rep < 6; rep++) {
            int rg = w * 6 + rep;             // 0..23
            int r  = rg * 8 + (l >> 3);
            int cg = (l & 7) ^ (r & 7);
            const bf16_t* gp = pnb + (size_t)r * DD + kc + cg * 8;
            GLOAD_LDS16(gp, BsB + rg * 1024);
        }
        // pn gt-class chunk: 5 KB, 5 insts total
        GLOAD_LDS16(basePn + kc, pnB + w * 1024);
        if (w == 0) GLOAD_LDS16(basePn2 + kc, pnB + 4096);
        __syncthreads();

        // MFMA
        #pragma unroll
        for (int ks = 0; ks < 4; ks++) {
            int ar  = w * 32 + am;
            int c0a = ks * 4 + q * 2;
            int ca0 = (c0a)     ^ (ar & 15);
            int ca1 = (c0a + 1) ^ (ar & 15);
            float4 a0 = *(const float4*)(AsB + ar * 256 + ca0 * 16);
            float4 a1 = *(const float4*)(AsB + ar * 256 + ca1 * 16);
            bf16x8 af;
            af[0] = (bf16_t)a0.x; af[1] = (bf16_t)a0.y; af[2] = (bf16_t)a0.z; af[3] = (bf16_t)a0.w;
            af[4] = (bf16_t)a1.x; af[5] = (bf16_t)a1.y; af[6] = (bf16_t)a1.z; af[7] = (bf16_t)a1.w;
            #pragma unroll
            for (int ct = 0; ct < 6; ct++) {
                int br = ct * 32 + am;
                int cb = (ks * 2 + q) ^ (br & 7);
                bf16x8 bf = *(const bf16x8*)(BsB + br * 128 + cb * 16);
                acc[ct] = __builtin_amdgcn_mfma_f32_32x32x16_bf16(af, bf, acc[ct], 0, 0, 0);
            }
        }

        // precise dots + fp64 norm partials (VALU pipe, same barrier window)
        if (uniB) {
            const char* pb = pnB + mh * 1280;
            #pragma unroll
            for (int cc2 = 0; cc2 < 8; cc2++) {
                int c = ch * 8 + cc2;
                int slot = (c ^ rp) * 16;
                float4 a0 = *(const float4*)(AsB + r0 * 256 + slot);
                float4 a1 = *(const float4*)(AsB + r1 * 256 + slot);
                ss0 += (double)a0.x*a0.x + (double)a0.y*a0.y + (double)a0.z*a0.z + (double)a0.w*a0.w;
                ss1 += (double)a1.x*a1.x + (double)a1.y*a1.y + (double)a1.z*a1.z + (double)a1.w*a1.w;
                #pragma unroll
                for (int j = 0; j < 5; j++) {
                    float4 b = *(const float4*)(pb + j * 256 + c * 16);
                    float v0 = a0.x*b.x; v0 = fmaf(a0.y,b.y,v0); v0 = fmaf(a0.z,b.z,v0); v0 = fmaf(a0.w,b.w,v0);
                    float v1 = a1.x*b.x; v1 = fmaf(a1.y,b.y,v1); v1 = fmaf(a1.z,b.z,v1); v1 = fmaf(a1.w,b.w,v1);
                    d0[j] += v0; d1[j] += v1;
                }
            }
        } else {
            const char* pb0 = pnB + sel0 * 2560 + mh * 1280;
            const char* pb1 = pnB + sel1 * 2560 + mh * 1280;
            #pragma unroll
            for (int cc2 = 0; cc2 < 8; cc2++) {
                int c = ch * 8 + cc2;
                int slot = (c ^ rp) * 16;
                float4 a0 = *(const float4*)(AsB + r0 * 256 + slot);
                float4 a1 = *(const float4*)(AsB + r1 * 256 + slot);
                ss0 += (double)a0.x*a0.x + (double)a0.y*a0.y + (double)a0.z*a0.z + (double)a0.w*a0.w;
                ss1 += (double)a1.x*a1.x + (double)a1.y*a1.y + (double)a1.z*a1.z + (double)a1.w*a1.w;
                #pragma unroll
                for (int j = 0; j < 5; j++) {
                    float4 b0 = *(const float4*)(pb0 + j * 256 + c * 16);
                    float4 b1 = *(const float4*)(pb1 + j * 256 + c * 16);
                    float v0 = a0.x*b0.x; v0 = fmaf(a0.y,b0.y,v0); v0 = fmaf(a0.z,b0.z,v0); v0 = fmaf(a0.w,b0.w,v0);
                    float v1 = a1.x*b1.x; v1 = fmaf(a1.y,b1.y,v1); v1 = fmaf(a1.z,b1.z,v1); v1 = fmaf(a1.w,b1.w,v1);
                    d0[j] += v0; d1[j] += v1;
                }
            }
        }
        __syncthreads();
    }

    // combine ch halves (xor lane bit0)
    #pragma unroll
    for (int j = 0; j < 5; j++) {
        d0[j] += __shfl_xor(d0[j], 1);
        d1[j] += __shfl_xor(d1[j], 1);
    }
    ss0 += __shfl_xor(ss0, 1);
    ss1 += __shfl_xor(ss1, 1);
    float inv0 = (float)(1.0 / fmax(sqrt(ss0), 1e-12));
    float inv1 = (float)(1.0 / fmax(sqrt(ss1), 1e-12));
    if ((l & 3) == 0) {                  // mh==0 && ch==0
        inv_f[nr0] = inv0; inv_f[nr1] = inv1;
        sNv[r0] = inv0;    sNv[r1] = inv1;
    }
    if (ch == 0) {
        #pragma unroll
        for (int j = 0; j < 5; j++) {
            Es[(size_t)(p0 + r0) * MM + mh * 5 + j] = exp(20.0 * (double)fabsf(d0[j] * inv0));
            Es[(size_t)(p0 + r1) * MM + mh * 5 + j] = exp(20.0 * (double)fabsf(d1[j] * inv1));
        }
    }
    __syncthreads();

    // epilogue: D[row][col]: col = ct*32 + (lane&31); row = (reg&3) + 8*(reg>>2) + 4*(lane>>5)
    // rows scatter to natural order via sRow
    #pragma unroll
    for (int ct = 0; ct < 6; ct++) {
        int col = ct * 32 + am;
        if (col < CC) {
            #pragma unroll
            for (int reg = 0; reg < 16; reg++) {
                int rl = w * 32 + (reg & 3) + 8 * (reg >> 2) + 4 * q;
                o0[(size_t)sRow[rl] * CC + col] = fabsf(acc[ct][reg] * sNv[rl]);
            }
        }
    }
}

// ---------------- per-row epilogue from o0: kpt_class, pred, conf_eff ----------------
__global__ __launch_bounds__(256) void k_epi2(const float* __restrict__ o0,
                                              const int* __restrict__ gt,
                                              const float* __restrict__ conf,
                                              const float* __restrict__ inv_f,
                                              const int* __restrict__ rank,
                                              float* __restrict__ o2,
                                              float* __restrict__ wq_s,
                                              float* __restrict__ wn_s) {
    __shared__ float S[64][CC + 1];
    int t = threadIdx.x;
    int row0 = blockIdx.x * 64;
    for (int idx = t; idx < 64 * CC; idx += 256) {
        int r = idx / CC, c = idx - r * CC;
        S[r][c] = o0[(size_t)(row0 + r) * CC + c];
    }
    __syncthreads();
    if (t < 64) {
        int n = row0 + t;
        float best = -1.f; int pred = 0;
        #pragma unroll
        for (int k = 0; k < NKPT; k++) {
            float mx = S[t][k * MM];
            #pragma unroll
            for (int m = 1; m < MM; m++) mx = fmaxf(mx, S[t][k * MM + m]);
            o2[(size_t)n * NKPT + k] = fminf(fmaxf(mx, 1e-4f), 1.f - 1e-4f);
            if (mx > best) { best = mx; pred = k; }
        }
        int cls = gt[n];
        float ce = (pred == cls) ? conf[n] : 0.f;
        int pos = rank[n];
        wq_s[pos] = ce * ce * inv_f[n];
        wn_s[pos] = ce;
    }
}

// ---------------- Sinkhorn column-sum of a (fp64) ----------------
__global__ __launch_bounds__(256) void k_colsumA(const double* __restrict__ Es,
                                                 const int* __restrict__ offsets,
                                                 double* __restrict__ A) {
    int k  = blockIdx.x / CHUNKS;
    int ch = blockIdx.x % CHUNKS;
    int j0 = offsets[k], j1 = offsets[k + 1];
    long long len = j1 - j0;
    int c0 = j0 + (int)(len * ch / CHUNKS);
    int c1 = j0 + (int)(len * (ch + 1) / CHUNKS);
    int t = threadIdx.x;
    double acc[MM];
    #pragma unroll
    for (int m = 0; m < MM; m++) acc[m] = 0.0;
    for (int j = c0 + t; j < c1; j += 256) {
        #pragma unroll
        for (int m = 0; m < MM; m++) acc[m] += Es[(size_t)j * MM + m];
    }
    __shared__ double red[4][MM];
    int lane = t & 63, w = t >> 6;
    #pragma unroll
    for (int m = 0; m < MM; m++) {
        double v = acc[m];
        for (int off = 32; off > 0; off >>= 1) v += __shfl_down(v, off);
        if (lane == 0) red[w][m] = v;
    }
    __syncthreads();
    if (t < MM) atomicAdd(&A[k * MM + t], red[0][t] + red[1][t] + red[2][t] + red[3][t]);
}

// ---------------- one Sinkhorn iteration ----------------
__global__ __launch_bounds__(256) void k_iter(const double* __restrict__ Es,
                                              const int* __restrict__ offsets,
                                              const int* __restrict__ counts,
                                              const double* __restrict__ colf,
                                              double* __restrict__ T) {
    int k  = blockIdx.x / CHUNKS;
    int ch = blockIdx.x % CHUNKS;
    int j0 = offsets[k], j1 = offsets[k + 1];
    long long len = j1 - j0;
    int c0 = j0 + (int)(len * ch / CHUNKS);
    int c1 = j0 + (int)(len * (ch + 1) / CHUNKS);
    int t = threadIdx.x;
    double cf[MM];
    #pragma unroll
    for (int m = 0; m < MM; m++) cf[m] = colf[k * MM + m];
    double Bk = (double)counts[k];
    double acc[MM];
    #pragma unroll
    for (int m = 0; m < MM; m++) acc[m] = 0.0;
    for (int j = c0 + t; j < c1; j += 256) {
        double e[MM], rs = 0.0;
        #pragma unroll
        for (int m = 0; m < MM; m++) { e[m] = Es[(size_t)j * MM + m]; rs += e[m] * cf[m]; }
        double rowf = 1.0 / (Bk * rs);
        #pragma unroll
        for (int m = 0; m < MM; m++) acc[m] += e[m] * rowf;
    }
    __shared__ double red[4][MM];
    int lane = t & 63, w = t >> 6;
    #pragma unroll
    for (int m = 0; m < MM; m++) {
        double v = acc[m];
        for (int off = 32; off > 0; off >>= 1) v += __shfl_down(v, off);
        if (lane == 0) red[w][m] = v;
    }
    __syncthreads();
    if (t < MM) atomicAdd(&T[k * MM + t], red[0][t] + red[1][t] + red[2][t] + red[3][t]);
}

__global__ __launch_bounds__(256) void k_colf1(const double* __restrict__ A,
                                               double* __restrict__ colf) {
    int t = threadIdx.x;
    __shared__ double red[256];
    red[t] = (t < CC) ? A[t] : 0.0;
    __syncthreads();
    for (int s = 128; s > 0; s >>= 1) { if (t < s) red[t] += red[t + s]; __syncthreads(); }
    if (t < CC) colf[t] = red[0] / (10.0 * A[t]);
}

__global__ __launch_bounds__(256) void k_colf(const double* __restrict__ T,
                                              double* __restrict__ colf) {
    int t = threadIdx.x;
    if (t < CC) colf[t] = 1.0 / (10.0 * T[t]);
}

// ---------------- final argmax -> proto_target, assign ----------------
__global__ __launch_bounds__(256) void k_argmax(const double* __restrict__ Es,
                                                const int* __restrict__ offsets,
                                                const double* __restrict__ colf3,
                                                const int* __restrict__ perm,
                                                float* __restrict__ o1,
                                                int* __restrict__ assign) {
    int k  = blockIdx.x / CHUNKS;
    int ch = blockIdx.x % CHUNKS;
    int j0 = offsets[k], j1 = offsets[k + 1];
    long long len = j1 - j0;
    int c0 = j0 + (int)(len * ch / CHUNKS);
    int c1 = j0 + (int)(len * (ch + 1) / CHUNKS);
    int t = threadIdx.x;
    double cf[MM];
    #pragma unroll
    for (int m = 0; m < MM; m++) cf[m] = colf3[k * MM + m];
    for (int j = c0 + t; j < c1; j += 256) {
        double bestv = Es[(size_t)j * MM] * cf[0];
        int bi = 0;
        #pragma unroll
        for (int m = 1; m < MM; m++) {
            double v = Es[(size_t)j * MM + m] * cf[m];
            if (v > bestv) { bestv = v; bi = m; }
        }
        o1[perm[j]] = (float)(bi + MM * k);
        assign[j] = bi;
    }
}

// ---------------- weighted gather of feats into f_raw[k,m,:], n_km ----------------
__global__ __launch_bounds__(256) void k_gather(const float* __restrict__ feats,
                                                const int* __restrict__ offsets,
                                                const int* __restrict__ perm,
                                                const int* __restrict__ assign,
                                                const float* __restrict__ wq_s,
                                                const float* __restrict__ wn_s,
                                                float* __restrict__ f_raw,
                                                float* __restrict__ nkm) {
    int c = blockIdx.x;            // 0..169
    int k = c / MM, m = c - k * MM;
    int ch = blockIdx.y;
    int j0 = offsets[k], j1 = offsets[k + 1];
    long long len = j1 - j0;
    int c0 = j0 + (int)(len * ch / GCH);
    int c1 = j0 + (int)(len * (ch + 1) / GCH);
    int t = threadIdx.x;
    float a0 = 0.f, a1 = 0.f, a2 = 0.f, nacc = 0.f;
    __shared__ int   als[256];
    __shared__ float wls[256];
    __shared__ int   rls[256];
    __shared__ float nls[256];
    for (int jb = c0; jb < c1; jb += 256) {
        int j = jb + t;
        if (j < c1) { als[t] = assign[j]; wls[t] = wq_s[j]; rls[t] = perm[j]; nls[t] = wn_s[j]; }
        __syncthreads();
        int lim = min(256, c1 - jb);
        for (int i = 0; i < lim; i++) {
            if (als[i] == m && wls[i] != 0.f) {
                float w = wls[i];
                const float* row = feats + (size_t)rls[i] * DD;
                a0 = fmaf(w, row[t], a0);
                a1 = fmaf(w, row[t + 256], a1);
                a2 = fmaf(w, row[t + 512], a2);
                if (t == 0) nacc += nls[i];
            }
        }
        __syncthreads();
    }
    atomicAdd(&f_raw[(size_t)c * DD + t], a0);
    atomicAdd(&f_raw[(size_t)c * DD + t + 256], a1);
    atomicAdd(&f_raw[(size_t)c * DD + t + 512], a2);
    if (t == 0) atomicAdd(&nkm[c], nacc);
}

// ---------------- new_protos epilogue ----------------
__global__ __launch_bounds__(256) void k_newproto(const float* __restrict__ f_raw,
                                                  const float* __restrict__ nkm,
                                                  const float* __restrict__ pn,
                                                  float* __restrict__ o3) {
    int c = blockIdx.x, t = threadIdx.x;
    int k = c / MM;
    float f0 = f_raw[(size_t)c * DD + t];
    float f1 = f_raw[(size_t)c * DD + t + 256];
    float f2 = f_raw[(size_t)c * DD + t + 512];
    __shared__ double red[256];
    red[t] = (double)f0 * f0 + (double)f1 * f1 + (double)f2 * f2;
    __syncthreads();
    for (int s = 128; s > 0; s >>= 1) { if (t < s) red[t] += red[t + s]; __syncthreads(); }
    float invf = (float)(1.0 / fmax(sqrt(red[0]), 1e-12));
    bool valid = (nkm[c] != 0.f);
    float hs = 0.f;
    #pragma unroll
    for (int m = 0; m < MM; m++) hs += nkm[k * MM + m];
    bool has = (hs > 0.f);
    float p0 = pn[(size_t)c * DD + t];
    float p1 = pn[(size_t)c * DD + t + 256];
    float p2 = pn[(size_t)c * DD + t + 512];
    float v0, v1, v2;
    if (has && valid) {
        v0 = 0.999f * p0 + 0.001f * (f0 * invf);
        v1 = 0.999f * p1 + 0.001f * (f1 * invf);
        v2 = 0.999f * p2 + 0.001f * (f2 * invf);
    } else { v0 = p0; v1 = p1; v2 = p2; }
    __syncthreads();
    red[t] = (double)v0 * v0 + (double)v1 * v1 + (double)v2 * v2;
    __syncthreads();
    for (int s = 128; s > 0; s >>= 1) { if (t < s) red[t] += red[t + s]; __syncthreads(); }
    float inv2 = (float)(1.0 / fmax(sqrt(red[0]), 1e-12));
    o3[(size_t)c * DD + t]       = v0 * inv2;
    o3[(size_t)c * DD + t + 256] = v1 * inv2;
    o3[(size_t)c * DD + t + 512] = v2 * inv2;
}

extern "C" void kernel_launch(void* const* d_in, const int* in_sizes, int n_in,
                              void* d_out, int out_size, void* d_ws, size_t ws_size,
                              hipStream_t stream) {
    const float* feats  = (const float*)d_in[0];
    const int*   gt     = (const int*)d_in[1];
    const float* conf   = (const float*)d_in[2];
    const float* protos = (const float*)d_in[3];

    float* o0 = (float*)d_out;                       // proto_logits  N x 170
    float* o1 = o0 + (size_t)NN * CC;                // proto_target  N
    float* o2 = o1 + NN;                             // kpt_class     N x 17
    float* o3 = o2 + (size_t)NN * NKPT;              // new_protos    170 x 768

    char* ws = (char*)d_ws;
    float*  inv_f  = (float*)(ws + 0);               // N f32
    float*  pn     = (float*)(ws + 524288);          // 170x768 f32
    bf16_t* pnb    = (bf16_t*)(ws + 1048576);        // 192x768 bf16
    float*  wq_s   = (float*)(ws + 1441792);         // N f32 (sorted)
    float*  wn_s   = (float*)(ws + 1966080);         // N f32 (sorted)
    int*    perm   = (int*)  (ws + 2490368);         // N i32
    int*    rka    = (int*)  (ws + 3014656);         // N i32: rank, later reused as assign
    double* Es     = (double*)(ws + 3538944);        // N x 10 f64
    char*   zz     = ws + 14024704;                  // zero zone start
    int*    counts = (int*)  (zz + 0);
    int*    cursor = (int*)  (zz + 128);
    int*    offs   = (int*)  (zz + 256);
    double* A      = (double*)(zz + 384);
    double* T1     = (double*)(zz + 384 + 2048);
    double* T2     = (double*)(zz + 384 + 4096);
    double* colf1  = (double*)(zz + 384 + 6144);
    double* colf2  = (double*)(zz + 384 + 8192);
    double* colf3  = (double*)(zz + 384 + 10240);
    float*  nkm    = (float*) (zz + 384 + 12288);
    float*  f_raw  = (float*) (zz + 384 + 12288 + 1024);
    size_t  zz_bytes = 384 + 12288 + 1024 + (size_t)CC * DD * 4;

    hipMemsetAsync(zz, 0, zz_bytes, stream);
    k_proto_norm<<<192, 256, 0, stream>>>(protos, pn, pnb);
    k_hist<<<512, 256, 0, stream>>>(gt, counts);
    k_prefix<<<1, 64, 0, stream>>>(counts, offs);
    k_rank<<<NN / 256, 256, 0, stream>>>(gt, offs, cursor, perm, rka);
    k_gemm<<<NN / 128, 256, 0, stream>>>(feats, pnb, pn, gt, perm, inv_f, Es, o0);
    k_epi2<<<NN / 64, 256, 0, stream>>>(o0, gt, conf, inv_f, rka, o2, wq_s, wn_s);
    k_colsumA<<<NKPT * CHUNKS, 256, 0, stream>>>(Es, offs, A);
    k_colf1<<<1, 256, 0, stream>>>(A, colf1);
    k_iter<<<NKPT * CHUNKS, 256, 0, stream>>>(Es, offs, counts, colf1, T1);
    k_colf<<<1, 256, 0, stream>>>(T1, colf2);
    k_iter<<<NKPT * CHUNKS, 256, 0, stream>>>(Es, offs, counts, colf2, T2);
    k_colf<<<1, 256, 0, stream>>>(T2, colf3);
    k_argmax<<<NKPT * CHUNKS, 256, 0, stream>>>(Es, offs, colf3, perm, o1, rka);
    dim3 gg(CC, GCH);
    k_gather<<<gg, 256, 0, stream>>>(feats, offs, perm, rka, wq_s, wn_s, f_raw, nkm);
    k_newproto<<<CC, 256, 0, stream>>>(f_raw, nkm, pn, o3);
}

// Round 3
// 874.941 us; speedup vs baseline: 1.3064x; 1.3064x over previous
//
#include <hip/hip_runtime.h>
#include <math.h>

#define NKPT 17
#define MM   10
#define DD   768
#define NN   131072
#define CC   (NKPT*MM)   // 170
#define CHUNKS 16
#define GCH2   4

typedef __bf16 bf16_t;
typedef bf16_t bf16x8 __attribute__((ext_vector_type(8)));
typedef float  f32x16 __attribute__((ext_vector_type(16)));

#define GLOAD_LDS16(g, s) \
    __builtin_amdgcn_global_load_lds((const __attribute__((address_space(1))) void*)(g), \
                                     (__attribute__((address_space(3))) void*)(s), 16, 0, 0)

// ---------------- proto norms: pn (fp32 normalized) + pnb (bf16, 192 rows, pad=0) ---------
__global__ __launch_bounds__(256) void k_proto_norm(const float* __restrict__ protos,
                                                    float* __restrict__ pn,
                                                    bf16_t* __restrict__ pnb) {
    int c = blockIdx.x;           // 0..191
    int t = threadIdx.x;          // 256
    if (c >= CC) {                // zero padding rows for the GEMM B-tile
        pnb[(size_t)c * DD + t]       = (bf16_t)0.f;
        pnb[(size_t)c * DD + t + 256] = (bf16_t)0.f;
        pnb[(size_t)c * DD + t + 512] = (bf16_t)0.f;
        return;
    }
    const float* row = protos + (size_t)c * DD;
    float v0 = row[t], v1 = row[t + 256], v2 = row[t + 512];
    double ss = (double)v0 * v0 + (double)v1 * v1 + (double)v2 * v2;
    __shared__ double red[256];
    red[t] = ss; __syncthreads();
    for (int s = 128; s > 0; s >>= 1) { if (t < s) red[t] += red[t + s]; __syncthreads(); }
    float invf = (float)(1.0 / fmax(sqrt(red[0]), 1e-12));
    float a0 = v0 * invf, a1 = v1 * invf, a2 = v2 * invf;
    pn[(size_t)c * DD + t]        = a0;
    pn[(size_t)c * DD + t + 256]  = a1;
    pn[(size_t)c * DD + t + 512]  = a2;
    pnb[(size_t)c * DD + t]       = (bf16_t)a0;
    pnb[(size_t)c * DD + t + 256] = (bf16_t)a1;
    pnb[(size_t)c * DD + t + 512] = (bf16_t)a2;
}

// ---------------- class histogram ----------------
__global__ __launch_bounds__(256) void k_hist(const int* __restrict__ gt,
                                              int* __restrict__ counts) {
    __shared__ int c[NKPT];
    int t = threadIdx.x;
    if (t < NKPT) c[t] = 0;
    __syncthreads();
    for (int i = blockIdx.x * blockDim.x + t; i < NN; i += gridDim.x * blockDim.x)
        atomicAdd(&c[gt[i]], 1);
    __syncthreads();
    if (t < NKPT) atomicAdd(&counts[t], c[t]);
}

__global__ void k_prefix(const int* __restrict__ counts, int* __restrict__ offsets) {
    if (threadIdx.x == 0 && blockIdx.x == 0) {
        int acc = 0;
        for (int k = 0; k < NKPT; k++) { offsets[k] = acc; acc += counts[k]; }
        offsets[NKPT] = acc;
    }
}

// ---------------- class-sort: perm (pos->row), rank (row->pos) ----------------
__global__ __launch_bounds__(256) void k_rank(const int* __restrict__ gt,
                                              const int* __restrict__ offs,
                                              int* __restrict__ cursor,
                                              int* __restrict__ perm,
                                              int* __restrict__ rank) {
    __shared__ int cnt[NKPT], base[NKPT];
    int t = threadIdx.x;
    if (t < NKPT) cnt[t] = 0;
    __syncthreads();
    int n = blockIdx.x * 256 + t;
    int cls = gt[n];
    int lr = atomicAdd(&cnt[cls], 1);
    __syncthreads();
    if (t < NKPT) base[t] = atomicAdd(&cursor[t], cnt[t]);
    __syncthreads();
    int p = offs[cls] + base[cls] + lr;
    perm[p] = n;
    rank[n] = p;
}

// ---------------- fused: feat norms + precise fp32 gt-class dots -> Es, + colsum(A) -------
// block = 256 thr = 4 waves; 32 class-sorted rows/block; 4 rows per wave-group.
// Sinkhorn column-sum A[k,m] folded in: per-wave register partials -> LDS -> global atomics.
__global__ __launch_bounds__(256) void k_prep(const float* __restrict__ feats,
                                              const float* __restrict__ pn,
                                              const int* __restrict__ gt,
                                              const int* __restrict__ perm,
                                              float* __restrict__ inv_f,
                                              double* __restrict__ Es,
                                              double* __restrict__ A) {
    __shared__ float pnS[MM * DD];    // 30 KB: the block's class prototypes
    int t = threadIdx.x, w = t >> 6, l = t & 63;
    int p0 = blockIdx.x * 32;
    int c0 = gt[perm[p0]];
    for (int idx = t; idx < MM * DD; idx += 256) pnS[idx] = pn[(size_t)c0 * (MM * DD) + idx];
    __syncthreads();
    double esum0 = 0.0, esum1 = 0.0;   // per-lane colsum partials (class c0 / other class)
    for (int g = 0; g < 2; g++) {
        int pg = p0 + w * 8 + g * 4;
        int nr[4], cl[4];
        bool uni = true;
        #pragma unroll
        for (int rr = 0; rr < 4; rr++) {
            nr[rr] = perm[pg + rr];
            cl[rr] = gt[nr[rr]];
            if (cl[rr] != c0) uni = false;
        }
        float4 fA[4][3];
        #pragma unroll
        for (int rr = 0; rr < 4; rr++) {
            const float4* r4 = (const float4*)(feats + (size_t)nr[rr] * DD);
            fA[rr][0] = r4[l]; fA[rr][1] = r4[l + 64]; fA[rr][2] = r4[l + 128];
        }
        // norms (fp64, butterfly)
        double ss[4];
        #pragma unroll
        for (int rr = 0; rr < 4; rr++) {
            float4 a = fA[rr][0], b = fA[rr][1], c = fA[rr][2];
            ss[rr] = (double)a.x*a.x + (double)a.y*a.y + (double)a.z*a.z + (double)a.w*a.w
                   + (double)b.x*b.x + (double)b.y*b.y + (double)b.z*b.z + (double)b.w*b.w
                   + (double)c.x*c.x + (double)c.y*c.y + (double)c.z*c.z + (double)c.w*c.w;
        }
        #pragma unroll
        for (int st = 1; st < 64; st <<= 1)
            #pragma unroll
            for (int rr = 0; rr < 4; rr++) ss[rr] += __shfl_xor(ss[rr], st);
        float inv[4];
        #pragma unroll
        for (int rr = 0; rr < 4; rr++) inv[rr] = (float)(1.0 / fmax(sqrt(ss[rr]), 1e-12));
        if (l == 0) {
            #pragma unroll
            for (int rr = 0; rr < 4; rr++) inv_f[nr[rr]] = inv[rr];
        }
        // 10 precise dots per row (fp32 partials + butterfly)
        float part[MM][4];
        if (uni) {
            #pragma unroll
            for (int m = 0; m < MM; m++) {
                const float4* P = (const float4*)(pnS + m * DD);
                float4 b0 = P[l], b1 = P[l + 64], b2 = P[l + 128];
                #pragma unroll
                for (int rr = 0; rr < 4; rr++) {
                    float4 a0 = fA[rr][0], a1 = fA[rr][1], a2 = fA[rr][2];
                    float v = a0.x*b0.x + a0.y*b0.y + a0.z*b0.z + a0.w*b0.w;
                    v = fmaf(a1.x, b1.x, v); v = fmaf(a1.y, b1.y, v);
                    v = fmaf(a1.z, b1.z, v); v = fmaf(a1.w, b1.w, v);
                    v = fmaf(a2.x, b2.x, v); v = fmaf(a2.y, b2.y, v);
                    v = fmaf(a2.z, b2.z, v); v = fmaf(a2.w, b2.w, v);
                    part[m][rr] = v;
                }
            }
        } else {
            #pragma unroll
            for (int m = 0; m < MM; m++) {
                #pragma unroll
                for (int rr = 0; rr < 4; rr++) {
                    const float4* P = (const float4*)(pn + (size_t)cl[rr] * (MM * DD) + m * DD);
                    float4 b0 = P[l], b1 = P[l + 64], b2 = P[l + 128];
                    float4 a0 = fA[rr][0], a1 = fA[rr][1], a2 = fA[rr][2];
                    float v = a0.x*b0.x + a0.y*b0.y + a0.z*b0.z + a0.w*b0.w;
                    v = fmaf(a1.x, b1.x, v); v = fmaf(a1.y, b1.y, v);
                    v = fmaf(a1.z, b1.z, v); v = fmaf(a1.w, b1.w, v);
                    v = fmaf(a2.x, b2.x, v); v = fmaf(a2.y, b2.y, v);
                    v = fmaf(a2.z, b2.z, v); v = fmaf(a2.w, b2.w, v);
                    part[m][rr] = v;
                }
            }
        }
        #pragma unroll
        for (int st = 1; st < 64; st <<= 1)
            #pragma unroll
            for (int m = 0; m < MM; m++)
                #pragma unroll
                for (int rr = 0; rr < 4; rr++) part[m][rr] += __shfl_xor(part[m][rr], st);
        if (l < MM) {
            #pragma unroll
            for (int rr = 0; rr < 4; rr++) {
                float v = part[0][rr];
                #pragma unroll
                for (int m = 1; m < MM; m++) v = (l == m) ? part[m][rr] : v;
                float sf = fabsf(v * inv[rr]);
                double es = exp(20.0 * (double)sf);
                Es[(size_t)(pg + rr) * MM + l] = es;
                if (cl[rr] == c0) esum0 += es; else esum1 += es;
            }
        }
    }
    // block-level colsum -> global A (sorted blocks span <= 2 classes)
    __shared__ double colA[4][2][MM];
    if (l < MM) { colA[w][0][l] = esum0; colA[w][1][l] = esum1; }
    __syncthreads();
    if (t < 2 * MM) {
        int sel = t / MM, m = t - sel * MM;
        double v = colA[0][sel][m] + colA[1][sel][m] + colA[2][sel][m] + colA[3][sel][m];
        int cls = sel ? gt[perm[p0 + 31]] : c0;
        if ((sel == 0 || cls != c0) && v != 0.0) atomicAdd(&A[cls * MM + m], v);
    }
}

// ---------------- bf16 MFMA GEMM: |(feats @ pnb^T) * inv_f| -> o0[N x 170] ----------------
// block 256 thr = 4 waves; tile 128 rows x 192 cols; BK = 64.  (round-1 verified form)
__global__ __launch_bounds__(256, 2) void k_gemm(const float* __restrict__ feats,
                                                 const bf16_t* __restrict__ pnb,
                                                 const float* __restrict__ inv_f,
                                                 float* __restrict__ o0) {
    __shared__ float  AsF[128 * 64];     // 32 KB fp32, 16B-chunk swizzled by (row&15)
    __shared__ bf16_t Bs[192 * 64];      // 24 KB bf16, 16B-chunk swizzled by (row&7)
    __shared__ float  sInv[128];
    int tid = threadIdx.x;
    int w = tid >> 6, l = tid & 63;
    int row0 = blockIdx.x * 128;
    if (tid < 128) sInv[tid] = inv_f[row0 + tid];
    f32x16 acc[6];
    #pragma unroll
    for (int ct = 0; ct < 6; ct++)
        #pragma unroll
        for (int i = 0; i < 16; i++) acc[ct][i] = 0.f;
    char* AsB = (char*)AsF;
    char* BsB = (char*)Bs;
    int am = l & 31, q = l >> 5;
    for (int kc = 0; kc < DD; kc += 64) {
        // A: 32 KB, 8 insts/wave, 4 rows per inst
        #pragma unroll
        for (int rep = 0; rep < 8; rep++) {
            int rg = w * 8 + rep;             // 0..31
            int r  = rg * 4 + (l >> 4);
            int cg = (l & 15) ^ (r & 15);
            const float* gp = feats + (size_t)(row0 + r) * DD + kc + cg * 4;
            GLOAD_LDS16(gp, AsB + rg * 1024);
        }
        // B: 24 KB, 6 insts/wave, 8 rows per inst
        #pragma unroll
        for (int rep = 0; rep < 6; rep++) {
            int rg = w * 6 + rep;             // 0..23
            int r  = rg * 8 + (l >> 3);
            int cg = (l & 7) ^ (r & 7);
            const bf16_t* gp = pnb + (size_t)r * DD + kc + cg * 8;
            GLOAD_LDS16(gp, BsB + rg * 1024);
        }
        __syncthreads();
        #pragma unroll
        for (int ks = 0; ks < 4; ks++) {
            int ar  = w * 32 + am;
            int c0a = ks * 4 + q * 2;
            int ca0 = (c0a)     ^ (ar & 15);
            int ca1 = (c0a + 1) ^ (ar & 15);
            float4 a0 = *(const float4*)(AsB + ar * 256 + ca0 * 16);
            float4 a1 = *(const float4*)(AsB + ar * 256 + ca1 * 16);
            bf16x8 af;
            af[0] = (bf16_t)a0.x; af[1] = (bf16_t)a0.y; af[2] = (bf16_t)a0.z; af[3] = (bf16_t)a0.w;
            af[4] = (bf16_t)a1.x; af[5] = (bf16_t)a1.y; af[6] = (bf16_t)a1.z; af[7] = (bf16_t)a1.w;
            #pragma unroll
            for (int ct = 0; ct < 6; ct++) {
                int br = ct * 32 + am;
                int cb = (ks * 2 + q) ^ (br & 7);
                bf16x8 bf = *(const bf16x8*)(BsB + br * 128 + cb * 16);
                acc[ct] = __builtin_amdgcn_mfma_f32_32x32x16_bf16(af, bf, acc[ct], 0, 0, 0);
            }
        }
        __syncthreads();
    }
    // epilogue: D[row][col]: col = ct*32 + (lane&31); row = (reg&3) + 8*(reg>>2) + 4*(lane>>5)
    #pragma unroll
    for (int ct = 0; ct < 6; ct++) {
        int col = ct * 32 + am;
        if (col < CC) {
            #pragma unroll
            for (int reg = 0; reg < 16; reg++) {
                int rl = w * 32 + (reg & 3) + 8 * (reg >> 2) + 4 * q;
                o0[(size_t)(row0 + rl) * CC + col] = fabsf(acc[ct][reg] * sInv[rl]);
            }
        }
    }
}

// ---------------- per-row epilogue from o0: kpt_class, pred, conf_eff ----------------
__global__ __launch_bounds__(256) void k_epi2(const float* __restrict__ o0,
                                              const int* __restrict__ gt,
                                              const float* __restrict__ conf,
                                              const float* __restrict__ inv_f,
                                              const int* __restrict__ rank,
                                              float* __restrict__ o2,
                                              float* __restrict__ wq_s,
                                              float* __restrict__ wn_s) {
    __shared__ float S[64][CC + 1];
    int t = threadIdx.x;
    int row0 = blockIdx.x * 64;
    for (int idx = t; idx < 64 * CC; idx += 256) {
        int r = idx / CC, c = idx - r * CC;
        S[r][c] = o0[(size_t)(row0 + r) * CC + c];
    }
    __syncthreads();
    if (t < 64) {
        int n = row0 + t;
        float best = -1.f; int pred = 0;
        #pragma unroll
        for (int k = 0; k < NKPT; k++) {
            float mx = S[t][k * MM];
            #pragma unroll
            for (int m = 1; m < MM; m++) mx = fmaxf(mx, S[t][k * MM + m]);
            o2[(size_t)n * NKPT + k] = fminf(fmaxf(mx, 1e-4f), 1.f - 1e-4f);
            if (mx > best) { best = mx; pred = k; }
        }
        int cls = gt[n];
        float ce = (pred == cls) ? conf[n] : 0.f;
        int pos = rank[n];
        wq_s[pos] = ce * ce * inv_f[n];
        wn_s[pos] = ce;
    }
}

// ---------------- one Sinkhorn iteration (colf folded in-block) ----------------
// first=1: cf[m] = (sum over all 170 of Ain) / (10*Ain[k*MM+m])   (== old colf1)
// first=0: cf[m] = 1 / (10*Ain[k*MM+m])                            (== old colf)
__global__ __launch_bounds__(256) void k_iter(const double* __restrict__ Es,
                                              const int* __restrict__ offsets,
                                              const int* __restrict__ counts,
                                              const double* __restrict__ Ain,
                                              int first,
                                              double* __restrict__ T) {
    int k  = blockIdx.x / CHUNKS;
    int ch = blockIdx.x % CHUNKS;
    int t = threadIdx.x;
    __shared__ double cfS[MM];
    __shared__ double sred[256];
    sred[t] = (t < CC) ? Ain[t] : 0.0;
    __syncthreads();
    if (first) {
        for (int s = 128; s > 0; s >>= 1) { if (t < s) sred[t] += sred[t + s]; __syncthreads(); }
        if (t < MM) cfS[t] = sred[0] / (10.0 * Ain[k * MM + t]);
    } else {
        if (t < MM) cfS[t] = 1.0 / (10.0 * Ain[k * MM + t]);
    }
    __syncthreads();
    int j0 = offsets[k], j1 = offsets[k + 1];
    long long len = j1 - j0;
    int c0 = j0 + (int)(len * ch / CHUNKS);
    int c1 = j0 + (int)(len * (ch + 1) / CHUNKS);
    double cf[MM];
    #pragma unroll
    for (int m = 0; m < MM; m++) cf[m] = cfS[m];
    double Bk = (double)counts[k];
    double acc[MM];
    #pragma unroll
    for (int m = 0; m < MM; m++) acc[m] = 0.0;
    for (int j = c0 + t; j < c1; j += 256) {
        double e[MM], rs = 0.0;
        #pragma unroll
        for (int m = 0; m < MM; m++) { e[m] = Es[(size_t)j * MM + m]; rs += e[m] * cf[m]; }
        double rowf = 1.0 / (Bk * rs);
        #pragma unroll
        for (int m = 0; m < MM; m++) acc[m] += e[m] * rowf;
    }
    __shared__ double red[4][MM];
    int lane = t & 63, w = t >> 6;
    #pragma unroll
    for (int m = 0; m < MM; m++) {
        double v = acc[m];
        for (int off = 32; off > 0; off >>= 1) v += __shfl_down(v, off);
        if (lane == 0) red[w][m] = v;
    }
    __syncthreads();
    if (t < MM) atomicAdd(&T[k * MM + t], red[0][t] + red[1][t] + red[2][t] + red[3][t]);
}

// ---------------- final argmax -> proto_target, assign, member counts ----------------
__global__ __launch_bounds__(256) void k_argmax(const double* __restrict__ Es,
                                                const int* __restrict__ offsets,
                                                const double* __restrict__ T2,
                                                const int* __restrict__ perm,
                                                const float* __restrict__ wq_s,
                                                float* __restrict__ o1,
                                                int* __restrict__ assign,
                                                int* __restrict__ ccnt) {
    int k  = blockIdx.x / CHUNKS;
    int ch = blockIdx.x % CHUNKS;
    int t = threadIdx.x;
    __shared__ double cfS[MM];
    if (t < MM) cfS[t] = 1.0 / (10.0 * T2[k * MM + t]);
    __syncthreads();
    int j0 = offsets[k], j1 = offsets[k + 1];
    long long len = j1 - j0;
    int c0 = j0 + (int)(len * ch / CHUNKS);
    int c1 = j0 + (int)(len * (ch + 1) / CHUNKS);
    double cf[MM];
    #pragma unroll
    for (int m = 0; m < MM; m++) cf[m] = cfS[m];
    for (int j = c0 + t; j < c1; j += 256) {
        double bestv = Es[(size_t)j * MM] * cf[0];
        int bi = 0;
        #pragma unroll
        for (int m = 1; m < MM; m++) {
            double v = Es[(size_t)j * MM + m] * cf[m];
            if (v > bestv) { bestv = v; bi = m; }
        }
        o1[perm[j]] = (float)(bi + MM * k);
        assign[j] = bi;
        if (wq_s[j] != 0.f) atomicAdd(&ccnt[k * MM + bi], 1);
    }
}

// ---------------- compact members of each (k,m) into dense lists ----------------
__global__ __launch_bounds__(256) void k_scatter(const int* __restrict__ offsets,
                                                 const int* __restrict__ perm,
                                                 const int* __restrict__ assign,
                                                 const float* __restrict__ wq_s,
                                                 const float* __restrict__ wn_s,
                                                 const int* __restrict__ ccnt,
                                                 int* __restrict__ ccur,
                                                 int* __restrict__ midx,
                                                 float* __restrict__ mw,
                                                 float* __restrict__ mn) {
    int k  = blockIdx.x / CHUNKS;
    int ch = blockIdx.x % CHUNKS;
    int t = threadIdx.x;
    __shared__ int cls_[CC];
    __shared__ int cbase[CC];
    if (t < CC) cls_[t] = ccnt[t];
    __syncthreads();
    if (t == 0) {
        int acc = 0;
        for (int i = 0; i < CC; i++) { cbase[i] = acc; acc += cls_[i]; }
    }
    __syncthreads();
    int j0 = offsets[k], j1 = offsets[k + 1];
    long long len = j1 - j0;
    int c0 = j0 + (int)(len * ch / CHUNKS);
    int c1 = j0 + (int)(len * (ch + 1) / CHUNKS);
    for (int j = c0 + t; j < c1; j += 256) {
        float wv = wq_s[j];
        if (wv != 0.f) {
            int c = k * MM + assign[j];
            int pos = atomicAdd(&ccur[c], 1);
            int dst = cbase[c] + pos;
            midx[dst] = perm[j];
            mw[dst]   = wv;
            mn[dst]   = wn_s[j];
        }
    }
}

// ---------------- dense weighted gather of feats into f_raw[k,m,:], n_km ----------------
__global__ __launch_bounds__(256) void k_gather2(const float* __restrict__ feats,
                                                 const int* __restrict__ ccnt,
                                                 const int* __restrict__ midx,
                                                 const float* __restrict__ mw,
                                                 const float* __restrict__ mn,
                                                 float* __restrict__ f_raw,
                                                 float* __restrict__ nkm) {
    int c = blockIdx.x;            // 0..169
    int ch = blockIdx.y;           // 0..GCH2-1
    int t = threadIdx.x;
    __shared__ int cls_[CC];
    __shared__ int sb[2];
    if (t < CC) cls_[t] = ccnt[t];
    __syncthreads();
    if (t == 0) {
        int acc = 0;
        for (int i = 0; i < c; i++) acc += cls_[i];
        sb[0] = acc; sb[1] = cls_[c];
    }
    __syncthreads();
    int base = sb[0], cnt = sb[1];
    int s = base + (int)((long long)cnt * ch / GCH2);
    int e = base + (int)((long long)cnt * (ch + 1) / GCH2);
    __shared__ int   rls[256];
    __shared__ float wls[256];
    float a00=0.f,a01=0.f,a02=0.f,a03=0.f;
    float a10=0.f,a11=0.f,a12=0.f,a13=0.f;
    float a20=0.f,a21=0.f,a22=0.f,a23=0.f;
    float nacc = 0.f;
    for (int jb = s; jb < e; jb += 256) {
        int j = jb + t;
        if (j < e) { rls[t] = midx[j]; wls[t] = mw[j]; nacc += mn[j]; }
        __syncthreads();
        int lim = min(256, e - jb);
        int i = 0;
        for (; i + 4 <= lim; i += 4) {
            int r0 = rls[i], r1 = rls[i+1], r2 = rls[i+2], r3 = rls[i+3];
            float w0 = wls[i], w1 = wls[i+1], w2 = wls[i+2], w3 = wls[i+3];
            const float* p0 = feats + (size_t)r0 * DD;
            const float* p1 = feats + (size_t)r1 * DD;
            const float* p2 = feats + (size_t)r2 * DD;
            const float* p3 = feats + (size_t)r3 * DD;
            a00 = fmaf(w0, p0[t],       a00); a01 = fmaf(w1, p1[t],       a01);
            a02 = fmaf(w2, p2[t],       a02); a03 = fmaf(w3, p3[t],       a03);
            a10 = fmaf(w0, p0[t + 256], a10); a11 = fmaf(w1, p1[t + 256], a11);
            a12 = fmaf(w2, p2[t + 256], a12); a13 = fmaf(w3, p3[t + 256], a13);
            a20 = fmaf(w0, p0[t + 512], a20); a21 = fmaf(w1, p1[t + 512], a21);
            a22 = fmaf(w2, p2[t + 512], a22); a23 = fmaf(w3, p3[t + 512], a23);
        }
        for (; i < lim; i++) {
            int r0 = rls[i]; float w0 = wls[i];
            const float* p0 = feats + (size_t)r0 * DD;
            a00 = fmaf(w0, p0[t],       a00);
            a10 = fmaf(w0, p0[t + 256], a10);
            a20 = fmaf(w0, p0[t + 512], a20);
        }
        __syncthreads();
    }
    float a0 = (a00 + a01) + (a02 + a03);
    float a1 = (a10 + a11) + (a12 + a13);
    float a2 = (a20 + a21) + (a22 + a23);
    if (e > s) {
        atomicAdd(&f_raw[(size_t)c * DD + t],       a0);
        atomicAdd(&f_raw[(size_t)c * DD + t + 256], a1);
        atomicAdd(&f_raw[(size_t)c * DD + t + 512], a2);
    }
    __shared__ float nred[256];
    nred[t] = nacc; __syncthreads();
    for (int st = 128; st > 0; st >>= 1) { if (t < st) nred[t] += nred[t + st]; __syncthreads(); }
    if (t == 0 && nred[0] != 0.f) atomicAdd(&nkm[c], nred[0]);
}

// ---------------- new_protos epilogue ----------------
__global__ __launch_bounds__(256) void k_newproto(const float* __restrict__ f_raw,
                                                  const float* __restrict__ nkm,
                                                  const float* __restrict__ pn,
                                                  float* __restrict__ o3) {
    int c = blockIdx.x, t = threadIdx.x;
    int k = c / MM;
    float f0 = f_raw[(size_t)c * DD + t];
    float f1 = f_raw[(size_t)c * DD + t + 256];
    float f2 = f_raw[(size_t)c * DD + t + 512];
    __shared__ double red[256];
    red[t] = (double)f0 * f0 + (double)f1 * f1 + (double)f2 * f2;
    __syncthreads();
    for (int s = 128; s > 0; s >>= 1) { if (t < s) red[t] += red[t + s]; __syncthreads(); }
    float invf = (float)(1.0 / fmax(sqrt(red[0]), 1e-12));
    bool valid = (nkm[c] != 0.f);
    float hs = 0.f;
    #pragma unroll
    for (int m = 0; m < MM; m++) hs += nkm[k * MM + m];
    bool has = (hs > 0.f);
    float p0 = pn[(size_t)c * DD + t];
    float p1 = pn[(size_t)c * DD + t + 256];
    float p2 = pn[(size_t)c * DD + t + 512];
    float v0, v1, v2;
    if (has && valid) {
        v0 = 0.999f * p0 + 0.001f * (f0 * invf);
        v1 = 0.999f * p1 + 0.001f * (f1 * invf);
        v2 = 0.999f * p2 + 0.001f * (f2 * invf);
    } else { v0 = p0; v1 = p1; v2 = p2; }
    __syncthreads();
    red[t] = (double)v0 * v0 + (double)v1 * v1 + (double)v2 * v2;
    __syncthreads();
    for (int s = 128; s > 0; s >>= 1) { if (t < s) red[t] += red[t + s]; __syncthreads(); }
    float inv2 = (float)(1.0 / fmax(sqrt(red[0]), 1e-12));
    o3[(size_t)c * DD + t]       = v0 * inv2;
    o3[(size_t)c * DD + t + 256] = v1 * inv2;
    o3[(size_t)c * DD + t + 512] = v2 * inv2;
}

extern "C" void kernel_launch(void* const* d_in, const int* in_sizes, int n_in,
                              void* d_out, int out_size, void* d_ws, size_t ws_size,
                              hipStream_t stream) {
    const float* feats  = (const float*)d_in[0];
    const int*   gt     = (const int*)d_in[1];
    const float* conf   = (const float*)d_in[2];
    const float* protos = (const float*)d_in[3];

    float* o0 = (float*)d_out;                       // proto_logits  N x 170
    float* o1 = o0 + (size_t)NN * CC;                // proto_target  N
    float* o2 = o1 + NN;                             // kpt_class     N x 17
    float* o3 = o2 + (size_t)NN * NKPT;              // new_protos    170 x 768

    char* ws = (char*)d_ws;
    float*  inv_f  = (float*)(ws + 0);               // N f32
    float*  pn     = (float*)(ws + 524288);          // 170x768 f32
    bf16_t* pnb    = (bf16_t*)(ws + 1048576);        // 192x768 bf16
    float*  wq_s   = (float*)(ws + 1441792);         // N f32 (sorted)
    float*  wn_s   = (float*)(ws + 1966080);         // N f32 (sorted)
    int*    perm   = (int*)  (ws + 2490368);         // N i32
    int*    rka    = (int*)  (ws + 3014656);         // N i32: rank, later reused as assign
    double* Es     = (double*)(ws + 3538944);        // N x 10 f64 (ends 14024704)
    char*   zz     = ws + 14024704;                  // zero zone start
    int*    counts = (int*)   (zz + 0);
    int*    cursor = (int*)   (zz + 128);
    int*    offs   = (int*)   (zz + 256);
    double* A      = (double*)(zz + 384);            // 170 f64 (pad 2048)
    double* T1     = (double*)(zz + 2432);
    double* T2     = (double*)(zz + 4480);
    int*    ccnt   = (int*)   (zz + 6528);           // 170 i32 (pad 768)
    int*    ccur   = (int*)   (zz + 7296);
    float*  nkm    = (float*) (zz + 8064);
    float*  f_raw  = (float*) (zz + 8832);           // 170x768 f32
    size_t  zz_bytes = 8832 + (size_t)CC * DD * 4;
    int*    midx   = (int*)  (ws + 16777216);        // N i32 (compacted member rows)
    float*  mw     = (float*)(ws + 17301504);        // N f32 (member weights ce^2*inv)
    float*  mn     = (float*)(ws + 17825792);        // N f32 (member weights ce)

    hipMemsetAsync(zz, 0, zz_bytes, stream);
    k_proto_norm<<<192, 256, 0, stream>>>(protos, pn, pnb);
    k_hist<<<512, 256, 0, stream>>>(gt, counts);
    k_prefix<<<1, 64, 0, stream>>>(counts, offs);
    k_rank<<<NN / 256, 256, 0, stream>>>(gt, offs, cursor, perm, rka);
    k_prep<<<NN / 32, 256, 0, stream>>>(feats, pn, gt, perm, inv_f, Es, A);
    k_gemm<<<NN / 128, 256, 0, stream>>>(feats, pnb, inv_f, o0);
    k_epi2<<<NN / 64, 256, 0, stream>>>(o0, gt, conf, inv_f, rka, o2, wq_s, wn_s);
    k_iter<<<NKPT * CHUNKS, 256, 0, stream>>>(Es, offs, counts, A, 1, T1);
    k_iter<<<NKPT * CHUNKS, 256, 0, stream>>>(Es, offs, counts, T1, 0, T2);
    k_argmax<<<NKPT * CHUNKS, 256, 0, stream>>>(Es, offs, T2, perm, wq_s, o1, rka, ccnt);
    k_scatter<<<NKPT * CHUNKS, 256, 0, stream>>>(offs, perm, rka, wq_s, wn_s, ccnt, ccur, midx, mw, mn);
    dim3 gg(CC, GCH2);
    k_gather2<<<gg, 256, 0, stream>>>(feats, ccnt, midx, mw, mn, f_raw, nkm);
    k_newproto<<<CC, 256, 0, stream>>>(f_raw, nkm, pn, o3);
}

// Round 4
// 719.355 us; speedup vs baseline: 1.5890x; 1.2163x over previous
//
#include <hip/hip_runtime.h>
#include <math.h>

#define NKPT 17
#define MM   10
#define DD   768
#define NN   131072
#define CC   (NKPT*MM)   // 170
#define CHUNKS 16
#define GCH2   4

typedef __bf16 bf16_t;
typedef bf16_t bf16x8 __attribute__((ext_vector_type(8)));
typedef float  f32x16 __attribute__((ext_vector_type(16)));

#define GLOAD_LDS16(g, s) \
    __builtin_amdgcn_global_load_lds((const __attribute__((address_space(1))) void*)(g), \
                                     (__attribute__((address_space(3))) void*)(s), 16, 0, 0)

// ---------------- proto norms: pn (fp32) + split-bf16 pnbh/pnbl (192 rows, pad=0) ---------
__global__ __launch_bounds__(256) void k_proto_norm(const float* __restrict__ protos,
                                                    float* __restrict__ pn,
                                                    bf16_t* __restrict__ pnbh,
                                                    bf16_t* __restrict__ pnbl) {
    int c = blockIdx.x;           // 0..191
    int t = threadIdx.x;          // 256
    if (c >= CC) {                // zero padding rows for the GEMM B-tile
        #pragma unroll
        for (int s = 0; s < 3; s++) {
            pnbh[(size_t)c * DD + t + s * 256] = (bf16_t)0.f;
            pnbl[(size_t)c * DD + t + s * 256] = (bf16_t)0.f;
        }
        return;
    }
    const float* row = protos + (size_t)c * DD;
    float v0 = row[t], v1 = row[t + 256], v2 = row[t + 512];
    double ss = (double)v0 * v0 + (double)v1 * v1 + (double)v2 * v2;
    __shared__ double red[256];
    red[t] = ss; __syncthreads();
    for (int s = 128; s > 0; s >>= 1) { if (t < s) red[t] += red[t + s]; __syncthreads(); }
    float invf = (float)(1.0 / fmax(sqrt(red[0]), 1e-12));
    float a0 = v0 * invf, a1 = v1 * invf, a2 = v2 * invf;
    pn[(size_t)c * DD + t]        = a0;
    pn[(size_t)c * DD + t + 256]  = a1;
    pn[(size_t)c * DD + t + 512]  = a2;
    float av[3] = {a0, a1, a2};
    #pragma unroll
    for (int s = 0; s < 3; s++) {
        bf16_t h = (bf16_t)av[s];
        bf16_t lo = (bf16_t)(av[s] - (float)h);
        pnbh[(size_t)c * DD + t + s * 256] = h;
        pnbl[(size_t)c * DD + t + s * 256] = lo;
    }
}

// ---------------- class histogram ----------------
__global__ __launch_bounds__(256) void k_hist(const int* __restrict__ gt,
                                              int* __restrict__ counts) {
    __shared__ int c[NKPT];
    int t = threadIdx.x;
    if (t < NKPT) c[t] = 0;
    __syncthreads();
    for (int i = blockIdx.x * blockDim.x + t; i < NN; i += gridDim.x * blockDim.x)
        atomicAdd(&c[gt[i]], 1);
    __syncthreads();
    if (t < NKPT) atomicAdd(&counts[t], c[t]);
}

__global__ void k_prefix(const int* __restrict__ counts, int* __restrict__ offsets) {
    if (threadIdx.x == 0 && blockIdx.x == 0) {
        int acc = 0;
        for (int k = 0; k < NKPT; k++) { offsets[k] = acc; acc += counts[k]; }
        offsets[NKPT] = acc;
    }
}

// ---------------- class-sort: perm (pos->row), rank (row->pos) ----------------
__global__ __launch_bounds__(256) void k_rank(const int* __restrict__ gt,
                                              const int* __restrict__ offs,
                                              int* __restrict__ cursor,
                                              int* __restrict__ perm,
                                              int* __restrict__ rank) {
    __shared__ int cnt[NKPT], base[NKPT];
    int t = threadIdx.x;
    if (t < NKPT) cnt[t] = 0;
    __syncthreads();
    int n = blockIdx.x * 256 + t;
    int cls = gt[n];
    int lr = atomicAdd(&cnt[cls], 1);
    __syncthreads();
    if (t < NKPT) base[t] = atomicAdd(&cursor[t], cnt[t]);
    __syncthreads();
    int p = offs[cls] + base[cls] + lr;
    perm[p] = n;
    rank[n] = p;
}

// ---------------- fused split-bf16 4-pass MFMA GEMM ----------------
// tile 64 rows x 192 cols; BK=64; 4 waves = 2(M-halves) x 2(N-groups of 3 ct).
// Produces: o0 = |dot*inv| (fp32-accurate), inv_f (fp64-accum norms, 1 shuffle),
// Es[rank[n]*10 + j] = exp(20*|sim_gtclass|) -- replaces k_prep entirely.
__global__ __launch_bounds__(256, 2) void k_gemm(const float* __restrict__ feats,
                                                 const bf16_t* __restrict__ pnbh,
                                                 const bf16_t* __restrict__ pnbl,
                                                 const int* __restrict__ gt,
                                                 const int* __restrict__ rank,
                                                 float* __restrict__ inv_f,
                                                 double* __restrict__ Es,
                                                 float* __restrict__ o0) {
    __shared__ __align__(16) char pool[65536];
    char* AsB = pool;             // 16 KB fp32 A (64 x 64), swizzle (r&15)
    char* BhB = pool + 16384;     // 24 KB bf16 B-hi (192 x 64), swizzle (r&7)
    char* BlB = pool + 40960;     // 24 KB bf16 B-lo (dead after K-loop; tail reused)
    float* sInvL = (float*)(pool + 40960);
    int*   sGt   = (int*)(pool + 41216);
    int*   sRank = (int*)(pool + 41472);
    int tid = threadIdx.x;
    int w = tid >> 6, l = tid & 63;
    int row0 = blockIdx.x * 64;
    int am = l & 31, q = l >> 5;
    int mh2 = w & 1;              // wave's M-half (rows mh2*32..+31)
    int ng  = w >> 1;             // wave's N-group (cols ng*96..+95)
    f32x16 acc[3];
    #pragma unroll
    for (int ct = 0; ct < 3; ct++)
        #pragma unroll
        for (int i = 0; i < 16; i++) acc[ct][i] = 0.f;
    double ss = 0.0;
    int ar = mh2 * 32 + am;
    for (int kc = 0; kc < DD; kc += 64) {
        // A: 16 KB, 4 insts/wave, 4 rows per inst
        #pragma unroll
        for (int rep = 0; rep < 4; rep++) {
            int rg = w * 4 + rep;             // 0..15
            int r  = rg * 4 + (l >> 4);
            int cg = (l & 15) ^ (r & 15);
            GLOAD_LDS16(feats + (size_t)(row0 + r) * DD + kc + cg * 4, AsB + rg * 1024);
        }
        // B hi+lo: 24 KB each, 6 insts/wave each, 8 rows per inst
        #pragma unroll
        for (int rep = 0; rep < 6; rep++) {
            int rg = w * 6 + rep;             // 0..23
            int r  = rg * 8 + (l >> 3);
            int cg = (l & 7) ^ (r & 7);
            GLOAD_LDS16(pnbh + (size_t)r * DD + kc + cg * 8, BhB + rg * 1024);
            GLOAD_LDS16(pnbl + (size_t)r * DD + kc + cg * 8, BlB + rg * 1024);
        }
        __syncthreads();
        #pragma unroll
        for (int ks = 0; ks < 4; ks++) {
            int c0a = ks * 4 + q * 2;
            float4 a0 = *(const float4*)(AsB + ar * 256 + ((c0a)     ^ (ar & 15)) * 16);
            float4 a1 = *(const float4*)(AsB + ar * 256 + ((c0a + 1) ^ (ar & 15)) * 16);
            ss += (double)a0.x*a0.x + (double)a0.y*a0.y + (double)a0.z*a0.z + (double)a0.w*a0.w
                + (double)a1.x*a1.x + (double)a1.y*a1.y + (double)a1.z*a1.z + (double)a1.w*a1.w;
            bf16x8 ah, al;
            { bf16_t h; float v;
              v=a0.x; h=(bf16_t)v; ah[0]=h; al[0]=(bf16_t)(v-(float)h);
              v=a0.y; h=(bf16_t)v; ah[1]=h; al[1]=(bf16_t)(v-(float)h);
              v=a0.z; h=(bf16_t)v; ah[2]=h; al[2]=(bf16_t)(v-(float)h);
              v=a0.w; h=(bf16_t)v; ah[3]=h; al[3]=(bf16_t)(v-(float)h);
              v=a1.x; h=(bf16_t)v; ah[4]=h; al[4]=(bf16_t)(v-(float)h);
              v=a1.y; h=(bf16_t)v; ah[5]=h; al[5]=(bf16_t)(v-(float)h);
              v=a1.z; h=(bf16_t)v; ah[6]=h; al[6]=(bf16_t)(v-(float)h);
              v=a1.w; h=(bf16_t)v; ah[7]=h; al[7]=(bf16_t)(v-(float)h); }
            #pragma unroll
            for (int ct = 0; ct < 3; ct++) {
                int br = (ng * 3 + ct) * 32 + am;
                int cb = ((ks * 2 + q) ^ (br & 7)) * 16;
                bf16x8 bh = *(const bf16x8*)(BhB + br * 128 + cb);
                bf16x8 bl = *(const bf16x8*)(BlB + br * 128 + cb);
                acc[ct] = __builtin_amdgcn_mfma_f32_32x32x16_bf16(ah, bh, acc[ct], 0, 0, 0);
                acc[ct] = __builtin_amdgcn_mfma_f32_32x32x16_bf16(ah, bl, acc[ct], 0, 0, 0);
                acc[ct] = __builtin_amdgcn_mfma_f32_32x32x16_bf16(al, bh, acc[ct], 0, 0, 0);
                acc[ct] = __builtin_amdgcn_mfma_f32_32x32x16_bf16(al, bl, acc[ct], 0, 0, 0);
            }
        }
        __syncthreads();
    }
    // norms: lane covered half the columns of row ar; partner is q^1 (lane^32)
    ss += __shfl_xor(ss, 32);
    float inv = (float)(1.0 / fmax(sqrt(ss), 1e-12));
    if (w < 2 && q == 0) {
        sInvL[mh2 * 32 + am] = inv;
        inv_f[row0 + mh2 * 32 + am] = inv;
    }
    if (tid < 64) {
        sGt[tid]   = gt[row0 + tid];
        sRank[tid] = rank[row0 + tid];
    }
    __syncthreads();
    // epilogue: D[row][col]: col = ctg*32 + am; row = mh2*32 + (reg&3) + 8*(reg>>2) + 4*q
    #pragma unroll
    for (int ct = 0; ct < 3; ct++) {
        int col = (ng * 3 + ct) * 32 + am;
        if (col < CC) {
            #pragma unroll
            for (int reg = 0; reg < 16; reg++) {
                int rl = mh2 * 32 + (reg & 3) + 8 * (reg >> 2) + 4 * q;
                float sv = fabsf(acc[ct][reg] * sInvL[rl]);
                o0[(size_t)(row0 + rl) * CC + col] = sv;
                int gtc = sGt[rl];
                unsigned j = (unsigned)(col - gtc * MM);
                if (j < (unsigned)MM)
                    Es[(size_t)sRank[rl] * MM + j] = exp(20.0 * (double)sv);
            }
        }
    }
}

// ---------------- per-row epilogue from o0: kpt_class, pred, conf_eff ----------------
__global__ __launch_bounds__(256) void k_epi2(const float* __restrict__ o0,
                                              const int* __restrict__ gt,
                                              const float* __restrict__ conf,
                                              const float* __restrict__ inv_f,
                                              const int* __restrict__ rank,
                                              float* __restrict__ o2,
                                              float* __restrict__ wq_s,
                                              float* __restrict__ wn_s) {
    __shared__ float S[64][CC + 1];
    int t = threadIdx.x;
    int row0 = blockIdx.x * 64;
    for (int idx = t; idx < 64 * CC; idx += 256) {
        int r = idx / CC, c = idx - r * CC;
        S[r][c] = o0[(size_t)(row0 + r) * CC + c];
    }
    __syncthreads();
    if (t < 64) {
        int n = row0 + t;
        float best = -1.f; int pred = 0;
        #pragma unroll
        for (int k = 0; k < NKPT; k++) {
            float mx = S[t][k * MM];
            #pragma unroll
            for (int m = 1; m < MM; m++) mx = fmaxf(mx, S[t][k * MM + m]);
            o2[(size_t)n * NKPT + k] = fminf(fmaxf(mx, 1e-4f), 1.f - 1e-4f);
            if (mx > best) { best = mx; pred = k; }
        }
        int cls = gt[n];
        float ce = (pred == cls) ? conf[n] : 0.f;
        int pos = rank[n];
        wq_s[pos] = ce * ce * inv_f[n];
        wn_s[pos] = ce;
    }
}

// ---------------- Sinkhorn column-sum of a (fp64) ----------------
__global__ __launch_bounds__(256) void k_colsumA(const double* __restrict__ Es,
                                                 const int* __restrict__ offsets,
                                                 double* __restrict__ A) {
    int k  = blockIdx.x / CHUNKS;
    int ch = blockIdx.x % CHUNKS;
    int j0 = offsets[k], j1 = offsets[k + 1];
    long long len = j1 - j0;
    int c0 = j0 + (int)(len * ch / CHUNKS);
    int c1 = j0 + (int)(len * (ch + 1) / CHUNKS);
    int t = threadIdx.x;
    double acc[MM];
    #pragma unroll
    for (int m = 0; m < MM; m++) acc[m] = 0.0;
    for (int j = c0 + t; j < c1; j += 256) {
        #pragma unroll
        for (int m = 0; m < MM; m++) acc[m] += Es[(size_t)j * MM + m];
    }
    __shared__ double red[4][MM];
    int lane = t & 63, w = t >> 6;
    #pragma unroll
    for (int m = 0; m < MM; m++) {
        double v = acc[m];
        for (int off = 32; off > 0; off >>= 1) v += __shfl_down(v, off);
        if (lane == 0) red[w][m] = v;
    }
    __syncthreads();
    if (t < MM) atomicAdd(&A[k * MM + t], red[0][t] + red[1][t] + red[2][t] + red[3][t]);
}

// ---------------- one Sinkhorn iteration (colf folded in-block) ----------------
__global__ __launch_bounds__(256) void k_iter(const double* __restrict__ Es,
                                              const int* __restrict__ offsets,
                                              const int* __restrict__ counts,
                                              const double* __restrict__ Ain,
                                              int first,
                                              double* __restrict__ T) {
    int k  = blockIdx.x / CHUNKS;
    int ch = blockIdx.x % CHUNKS;
    int t = threadIdx.x;
    __shared__ double cfS[MM];
    __shared__ double sred[256];
    sred[t] = (t < CC) ? Ain[t] : 0.0;
    __syncthreads();
    if (first) {
        for (int s = 128; s > 0; s >>= 1) { if (t < s) sred[t] += sred[t + s]; __syncthreads(); }
        if (t < MM) cfS[t] = sred[0] / (10.0 * Ain[k * MM + t]);
    } else {
        if (t < MM) cfS[t] = 1.0 / (10.0 * Ain[k * MM + t]);
    }
    __syncthreads();
    int j0 = offsets[k], j1 = offsets[k + 1];
    long long len = j1 - j0;
    int c0 = j0 + (int)(len * ch / CHUNKS);
    int c1 = j0 + (int)(len * (ch + 1) / CHUNKS);
    double cf[MM];
    #pragma unroll
    for (int m = 0; m < MM; m++) cf[m] = cfS[m];
    double Bk = (double)counts[k];
    double acc[MM];
    #pragma unroll
    for (int m = 0; m < MM; m++) acc[m] = 0.0;
    for (int j = c0 + t; j < c1; j += 256) {
        double e[MM], rs = 0.0;
        #pragma unroll
        for (int m = 0; m < MM; m++) { e[m] = Es[(size_t)j * MM + m]; rs += e[m] * cf[m]; }
        double rowf = 1.0 / (Bk * rs);
        #pragma unroll
        for (int m = 0; m < MM; m++) acc[m] += e[m] * rowf;
    }
    __shared__ double red[4][MM];
    int lane = t & 63, w = t >> 6;
    #pragma unroll
    for (int m = 0; m < MM; m++) {
        double v = acc[m];
        for (int off = 32; off > 0; off >>= 1) v += __shfl_down(v, off);
        if (lane == 0) red[w][m] = v;
    }
    __syncthreads();
    if (t < MM) atomicAdd(&T[k * MM + t], red[0][t] + red[1][t] + red[2][t] + red[3][t]);
}

// ---------------- final argmax -> proto_target, assign, member counts ----------------
__global__ __launch_bounds__(256) void k_argmax(const double* __restrict__ Es,
                                                const int* __restrict__ offsets,
                                                const double* __restrict__ T2,
                                                const int* __restrict__ perm,
                                                const float* __restrict__ wq_s,
                                                float* __restrict__ o1,
                                                int* __restrict__ assign,
                                                int* __restrict__ ccnt) {
    int k  = blockIdx.x / CHUNKS;
    int ch = blockIdx.x % CHUNKS;
    int t = threadIdx.x;
    __shared__ double cfS[MM];
    if (t < MM) cfS[t] = 1.0 / (10.0 * T2[k * MM + t]);
    __syncthreads();
    int j0 = offsets[k], j1 = offsets[k + 1];
    long long len = j1 - j0;
    int c0 = j0 + (int)(len * ch / CHUNKS);
    int c1 = j0 + (int)(len * (ch + 1) / CHUNKS);
    double cf[MM];
    #pragma unroll
    for (int m = 0; m < MM; m++) cf[m] = cfS[m];
    for (int j = c0 + t; j < c1; j += 256) {
        double bestv = Es[(size_t)j * MM] * cf[0];
        int bi = 0;
        #pragma unroll
        for (int m = 1; m < MM; m++) {
            double v = Es[(size_t)j * MM + m] * cf[m];
            if (v > bestv) { bestv = v; bi = m; }
        }
        o1[perm[j]] = (float)(bi + MM * k);
        assign[j] = bi;
        if (wq_s[j] != 0.f) atomicAdd(&ccnt[k * MM + bi], 1);
    }
}

// ---------------- compact members of each (k,m) into dense lists ----------------
__global__ __launch_bounds__(256) void k_scatter(const int* __restrict__ offsets,
                                                 const int* __restrict__ perm,
                                                 const int* __restrict__ assign,
                                                 const float* __restrict__ wq_s,
                                                 const float* __restrict__ wn_s,
                                                 const int* __restrict__ ccnt,
                                                 int* __restrict__ ccur,
                                                 int* __restrict__ midx,
                                                 float* __restrict__ mw,
                                                 float* __restrict__ mn) {
    int k  = blockIdx.x / CHUNKS;
    int ch = blockIdx.x % CHUNKS;
    int t = threadIdx.x;
    __shared__ int cls_[CC];
    __shared__ int cbase[CC];
    if (t < CC) cls_[t] = ccnt[t];
    __syncthreads();
    if (t == 0) {
        int acc = 0;
        for (int i = 0; i < CC; i++) { cbase[i] = acc; acc += cls_[i]; }
    }
    __syncthreads();
    int j0 = offsets[k], j1 = offsets[k + 1];
    long long len = j1 - j0;
    int c0 = j0 + (int)(len * ch / CHUNKS);
    int c1 = j0 + (int)(len * (ch + 1) / CHUNKS);
    for (int j = c0 + t; j < c1; j += 256) {
        float wv = wq_s[j];
        if (wv != 0.f) {
            int c = k * MM + assign[j];
            int pos = atomicAdd(&ccur[c], 1);
            int dst = cbase[c] + pos;
            midx[dst] = perm[j];
            mw[dst]   = wv;
            mn[dst]   = wn_s[j];
        }
    }
}

// ---------------- dense weighted gather of feats into f_raw[k,m,:], n_km ----------------
__global__ __launch_bounds__(256) void k_gather2(const float* __restrict__ feats,
                                                 const int* __restrict__ ccnt,
                                                 const int* __restrict__ midx,
                                                 const float* __restrict__ mw,
                                                 const float* __restrict__ mn,
                                                 float* __restrict__ f_raw,
                                                 float* __restrict__ nkm) {
    int c = blockIdx.x;            // 0..169
    int ch = blockIdx.y;           // 0..GCH2-1
    int t = threadIdx.x;
    __shared__ int cls_[CC];
    __shared__ int sb[2];
    if (t < CC) cls_[t] = ccnt[t];
    __syncthreads();
    if (t == 0) {
        int acc = 0;
        for (int i = 0; i < c; i++) acc += cls_[i];
        sb[0] = acc; sb[1] = cls_[c];
    }
    __syncthreads();
    int base = sb[0], cnt = sb[1];
    int s = base + (int)((long long)cnt * ch / GCH2);
    int e = base + (int)((long long)cnt * (ch + 1) / GCH2);
    __shared__ int   rls[256];
    __shared__ float wls[256];
    float a00=0.f,a01=0.f,a02=0.f,a03=0.f;
    float a10=0.f,a11=0.f,a12=0.f,a13=0.f;
    float a20=0.f,a21=0.f,a22=0.f,a23=0.f;
    float nacc = 0.f;
    for (int jb = s; jb < e; jb += 256) {
        int j = jb + t;
        if (j < e) { rls[t] = midx[j]; wls[t] = mw[j]; nacc += mn[j]; }
        __syncthreads();
        int lim = min(256, e - jb);
        int i = 0;
        for (; i + 4 <= lim; i += 4) {
            int r0 = rls[i], r1 = rls[i+1], r2 = rls[i+2], r3 = rls[i+3];
            float w0 = wls[i], w1 = wls[i+1], w2 = wls[i+2], w3 = wls[i+3];
            const float* p0 = feats + (size_t)r0 * DD;
            const float* p1 = feats + (size_t)r1 * DD;
            const float* p2 = feats + (size_t)r2 * DD;
            const float* p3 = feats + (size_t)r3 * DD;
            a00 = fmaf(w0, p0[t],       a00); a01 = fmaf(w1, p1[t],       a01);
            a02 = fmaf(w2, p2[t],       a02); a03 = fmaf(w3, p3[t],       a03);
            a10 = fmaf(w0, p0[t + 256], a10); a11 = fmaf(w1, p1[t + 256], a11);
            a12 = fmaf(w2, p2[t + 256], a12); a13 = fmaf(w3, p3[t + 256], a13);
            a20 = fmaf(w0, p0[t + 512], a20); a21 = fmaf(w1, p1[t + 512], a21);
            a22 = fmaf(w2, p2[t + 512], a22); a23 = fmaf(w3, p3[t + 512], a23);
        }
        for (; i < lim; i++) {
            int r0 = rls[i]; float w0 = wls[i];
            const float* p0 = feats + (size_t)r0 * DD;
            a00 = fmaf(w0, p0[t],       a00);
            a10 = fmaf(w0, p0[t + 256], a10);
            a20 = fmaf(w0, p0[t + 512], a20);
        }
        __syncthreads();
    }
    float a0 = (a00 + a01) + (a02 + a03);
    float a1 = (a10 + a11) + (a12 + a13);
    float a2 = (a20 + a21) + (a22 + a23);
    if (e > s) {
        atomicAdd(&f_raw[(size_t)c * DD + t],       a0);
        atomicAdd(&f_raw[(size_t)c * DD + t + 256], a1);
        atomicAdd(&f_raw[(size_t)c * DD + t + 512], a2);
    }
    __shared__ float nred[256];
    nred[t] = nacc; __syncthreads();
    for (int st = 128; st > 0; st >>= 1) { if (t < st) nred[t] += nred[t + st]; __syncthreads(); }
    if (t == 0 && nred[0] != 0.f) atomicAdd(&nkm[c], nred[0]);
}

// ---------------- new_protos epilogue ----------------
__global__ __launch_bounds__(256) void k_newproto(const float* __restrict__ f_raw,
                                                  const float* __restrict__ nkm,
                                                  const float* __restrict__ pn,
                                                  float* __restrict__ o3) {
    int c = blockIdx.x, t = threadIdx.x;
    int k = c / MM;
    float f0 = f_raw[(size_t)c * DD + t];
    float f1 = f_raw[(size_t)c * DD + t + 256];
    float f2 = f_raw[(size_t)c * DD + t + 512];
    __shared__ double red[256];
    red[t] = (double)f0 * f0 + (double)f1 * f1 + (double)f2 * f2;
    __syncthreads();
    for (int s = 128; s > 0; s >>= 1) { if (t < s) red[t] += red[t + s]; __syncthreads(); }
    float invf = (float)(1.0 / fmax(sqrt(red[0]), 1e-12));
    bool valid = (nkm[c] != 0.f);
    float hs = 0.f;
    #pragma unroll
    for (int m = 0; m < MM; m++) hs += nkm[k * MM + m];
    bool has = (hs > 0.f);
    float p0 = pn[(size_t)c * DD + t];
    float p1 = pn[(size_t)c * DD + t + 256];
    float p2 = pn[(size_t)c * DD + t + 512];
    float v0, v1, v2;
    if (has && valid) {
        v0 = 0.999f * p0 + 0.001f * (f0 * invf);
        v1 = 0.999f * p1 + 0.001f * (f1 * invf);
        v2 = 0.999f * p2 + 0.001f * (f2 * invf);
    } else { v0 = p0; v1 = p1; v2 = p2; }
    __syncthreads();
    red[t] = (double)v0 * v0 + (double)v1 * v1 + (double)v2 * v2;
    __syncthreads();
    for (int s = 128; s > 0; s >>= 1) { if (t < s) red[t] += red[t + s]; __syncthreads(); }
    float inv2 = (float)(1.0 / fmax(sqrt(red[0]), 1e-12));
    o3[(size_t)c * DD + t]       = v0 * inv2;
    o3[(size_t)c * DD + t + 256] = v1 * inv2;
    o3[(size_t)c * DD + t + 512] = v2 * inv2;
}

extern "C" void kernel_launch(void* const* d_in, const int* in_sizes, int n_in,
                              void* d_out, int out_size, void* d_ws, size_t ws_size,
                              hipStream_t stream) {
    const float* feats  = (const float*)d_in[0];
    const int*   gt     = (const int*)d_in[1];
    const float* conf   = (const float*)d_in[2];
    const float* protos = (const float*)d_in[3];

    float* o0 = (float*)d_out;                       // proto_logits  N x 170
    float* o1 = o0 + (size_t)NN * CC;                // proto_target  N
    float* o2 = o1 + NN;                             // kpt_class     N x 17
    float* o3 = o2 + (size_t)NN * NKPT;              // new_protos    170 x 768

    char* ws = (char*)d_ws;
    float*  inv_f  = (float*)(ws + 0);               // N f32
    float*  pn     = (float*)(ws + 524288);          // 170x768 f32
    bf16_t* pnbh   = (bf16_t*)(ws + 1048576);        // 192x768 bf16 (hi)
    bf16_t* pnbl   = (bf16_t*)(ws + 1441792);        // 192x768 bf16 (lo)
    float*  wq_s   = (float*)(ws + 1835008);         // N f32 (sorted)
    float*  wn_s   = (float*)(ws + 2359296);         // N f32 (sorted)
    int*    perm   = (int*)  (ws + 2883584);         // N i32
    int*    rka    = (int*)  (ws + 3407872);         // N i32: rank, later reused as assign
    double* Es     = (double*)(ws + 3932160);        // N x 10 f64 (ends 14417920)
    char*   zz     = ws + 14417920;                  // zero zone start
    int*    counts = (int*)   (zz + 0);
    int*    cursor = (int*)   (zz + 128);
    int*    offs   = (int*)   (zz + 256);
    double* A      = (double*)(zz + 384);            // 170 f64
    double* T1     = (double*)(zz + 2432);
    double* T2     = (double*)(zz + 4480);
    int*    ccnt   = (int*)   (zz + 6528);           // 170 i32
    int*    ccur   = (int*)   (zz + 7296);
    float*  nkm    = (float*) (zz + 8064);
    float*  f_raw  = (float*) (zz + 8832);           // 170x768 f32
    size_t  zz_bytes = 8832 + (size_t)CC * DD * 4;
    int*    midx   = (int*)  (ws + 15728640);        // N i32 (compacted member rows)
    float*  mw     = (float*)(ws + 16252928);        // N f32
    float*  mn     = (float*)(ws + 16777216);        // N f32

    hipMemsetAsync(zz, 0, zz_bytes, stream);
    k_proto_norm<<<192, 256, 0, stream>>>(protos, pn, pnbh, pnbl);
    k_hist<<<512, 256, 0, stream>>>(gt, counts);
    k_prefix<<<1, 64, 0, stream>>>(counts, offs);
    k_rank<<<NN / 256, 256, 0, stream>>>(gt, offs, cursor, perm, rka);
    k_gemm<<<NN / 64, 256, 0, stream>>>(feats, pnbh, pnbl, gt, rka, inv_f, Es, o0);
    k_epi2<<<NN / 64, 256, 0, stream>>>(o0, gt, conf, inv_f, rka, o2, wq_s, wn_s);
    k_colsumA<<<NKPT * CHUNKS, 256, 0, stream>>>(Es, offs, A);
    k_iter<<<NKPT * CHUNKS, 256, 0, stream>>>(Es, offs, counts, A, 1, T1);
    k_iter<<<NKPT * CHUNKS, 256, 0, stream>>>(Es, offs, counts, T1, 0, T2);
    k_argmax<<<NKPT * CHUNKS, 256, 0, stream>>>(Es, offs, T2, perm, wq_s, o1, rka, ccnt);
    k_scatter<<<NKPT * CHUNKS, 256, 0, stream>>>(offs, perm, rka, wq_s, wn_s, ccnt, ccur, midx, mw, mn);
    dim3 gg(CC, GCH2);
    k_gather2<<<gg, 256, 0, stream>>>(feats, ccnt, midx, mw, mn, f_raw, nkm);
    k_newproto<<<CC, 256, 0, stream>>>(f_raw, nkm, pn, o3);
}